// Round 2
// baseline (457.031 us; speedup 1.0000x reference)
//
#include <hip/hip_runtime.h>
#include <hip/hip_bf16.h>
#include <stdint.h>

#define B_   4
#define N_   4096
#define HID_ 768
#define H_   12
#define DH_  64
#define NB_  266
#define NBP_ 288          // NB padded to multiple of 32
#define EPS_ 1e-4f
#define RATIO_ 0.06131393f  // 266^-0.5

typedef unsigned short u16;
typedef __attribute__((ext_vector_type(8))) short short8;
typedef __attribute__((ext_vector_type(4))) float floatx4;

__device__ __forceinline__ u16 f2b(float f) {
  __hip_bfloat16 h = __float2bfloat16(f);
  return *reinterpret_cast<u16*>(&h);
}
__device__ __forceinline__ float b2f(u16 u) {
  union { unsigned u; float f; } x; x.u = ((unsigned)u) << 16; return x.f;
}
__device__ __forceinline__ unsigned fmap(float x) {
  unsigned u = __float_as_uint(x);
  return (u & 0x80000000u) ? ~u : (u | 0x80000000u);
}
__device__ __forceinline__ float funmap(unsigned u) {
  unsigned b = (u & 0x80000000u) ? (u & 0x7FFFFFFFu) : ~u;
  return __uint_as_float(b);
}
// async global->LDS, 16B per lane; lds base must be wave-uniform
__device__ __forceinline__ void gl16(const u16* g, u16* l) {
  __builtin_amdgcn_global_load_lds(
      (const __attribute__((address_space(1))) void*)g,
      (__attribute__((address_space(3))) void*)l, 16, 0, 0);
}

// ---------------- converts / init ----------------
__global__ void k_convert4(const float4* __restrict__ src, uint2* __restrict__ dst, int n4) {
  int i = blockIdx.x * 256 + threadIdx.x;
  if (i >= n4) return;
  float4 v = src[i];
  union { u16 s[4]; uint2 u; } pk;
  pk.s[0] = f2b(v.x); pk.s[1] = f2b(v.y); pk.s[2] = f2b(v.z); pk.s[3] = f2b(v.w);
  dst[i] = pk.u;
}

__global__ void k_prep_proj(const float* __restrict__ proj, u16* __restrict__ dst) {
  int i = blockIdx.x * 256 + threadIdx.x;          // NBP_*DH_ = 18432
  if (i >= NBP_ * DH_) return;
  int j = i / DH_, d = i - j * DH_;
  float v = (j < NB_) ? proj[j * DH_ + d] * 0.35355339059327373f : 0.f;  // fold dn
  dst[i] = f2b(v);
}

__global__ void k_init(float* __restrict__ zf, unsigned* __restrict__ mbuf, int nf) {
  int i = blockIdx.x * 256 + threadIdx.x;
  if (i < nf) zf[i] = 0.f;
  if (i < B_ * H_) mbuf[i] = 0u;
}

// ---------------- QKV GEMM: m97 structure (global_load_lds w=16, 128x128, BK=32) ----------------
__global__ __launch_bounds__(256) void k_qkv(
    const u16* __restrict__ hsb, const u16* __restrict__ wb,
    const float* __restrict__ bq, const float* __restrict__ bk, const float* __restrict__ bv,
    u16* __restrict__ qb, u16* __restrict__ kb, u16* __restrict__ vb) {
  __shared__ u16 At[128 * 32];
  __shared__ u16 Bt[128 * 32];
  const int m0 = blockIdx.x * 128;
  const int bn = blockIdx.y;
  const int sel = bn / 6;                  // 0:q 1:k 2:v
  const int or0 = (bn % 6) * 128;
  const u16* W = wb + (size_t)sel * HID_ * HID_;
  const int t = threadIdx.x, lane = t & 63, wv = t >> 6;
  const int wr = (wv >> 1) * 64, wc = (wv & 1) * 64;
  const int lm = lane & 15, lq = lane >> 4;
  // staging: wave w covers rows [w*32, w*32+32), 2 instrs x 16 rows, lane: row=lane/4, col=(lane&3)*8
  const int srow = wv * 32 + (lane >> 2);
  const int scol = (lane & 3) * 8;
  const u16* gA0 = hsb + (size_t)(m0 + srow) * HID_ + scol;
  const u16* gA1 = gA0 + 16 * HID_;
  const u16* gB0 = W + (size_t)(or0 + srow) * HID_ + scol;
  const u16* gB1 = gB0 + 16 * HID_;
  u16* lA = At + wv * 1024;   // 32 rows * 32 u16
  u16* lB = Bt + wv * 1024;
  floatx4 acc[4][4];
#pragma unroll
  for (int i = 0; i < 4; i++)
#pragma unroll
    for (int j = 0; j < 4; j++) acc[i][j] = (floatx4){0.f, 0.f, 0.f, 0.f};

  for (int k0 = 0; k0 < HID_; k0 += 32) {
    __syncthreads();
    gl16(gA0 + k0, lA);
    gl16(gA1 + k0, lA + 512);
    gl16(gB0 + k0, lB);
    gl16(gB1 + k0, lB + 512);
    __syncthreads();
    short8 af[4], bfr[4];
#pragma unroll
    for (int mt = 0; mt < 4; mt++) af[mt] = *(const short8*)&At[(wr + mt * 16 + lm) * 32 + lq * 8];
#pragma unroll
    for (int nt = 0; nt < 4; nt++) bfr[nt] = *(const short8*)&Bt[(wc + nt * 16 + lm) * 32 + lq * 8];
#pragma unroll
    for (int mt = 0; mt < 4; mt++)
#pragma unroll
      for (int nt = 0; nt < 4; nt++)
        acc[mt][nt] = __builtin_amdgcn_mfma_f32_16x16x32_bf16(af[mt], bfr[nt], acc[mt][nt], 0, 0, 0);
  }
  const float* bias = (sel == 0) ? bq : (sel == 1) ? bk : bv;
  u16* dst = (sel == 0) ? qb : (sel == 1) ? kb : vb;
#pragma unroll
  for (int mt = 0; mt < 4; mt++) {
#pragma unroll
    for (int nt = 0; nt < 4; nt++) {
      int lc = or0 + wc + nt * 16 + lm;
      float bb = bias[lc];
#pragma unroll
      for (int r = 0; r < 4; r++) {
        int row = m0 + wr + mt * 16 + lq * 4 + r;
        dst[(size_t)row * HID_ + lc] = f2b(acc[mt][nt][r] + bb);
      }
    }
  }
}

// ---------------- v transpose: vT[bh][dv][n] with permuted n-order within 32-blocks ----------------
// perm: storage pos q (0..31) <-> n = ((q>>2)&1)*16 + (q>>3)*4 + (q&3)
__global__ __launch_bounds__(256) void k_vt(const u16* __restrict__ vb, u16* __restrict__ vT) {
  __shared__ u16 tile[64][72];
  const int bh = blockIdx.y, b = bh / H_, h = bh - b * H_;
  const int nc = blockIdx.x * 64;
  const int t = threadIdx.x;
#pragma unroll
  for (int i = 0; i < 2; i++) {
    int lin = t + i * 256;
    int r = lin >> 3, c8 = (lin & 7) * 8;
    *(uint4*)&tile[r][c8] = *(const uint4*)(vb + (size_t)(b * N_ + nc + r) * HID_ + h * DH_ + c8);
  }
  __syncthreads();
#pragma unroll
  for (int i = 0; i < 2; i++) {
    int lin = t + i * 256;
    int dv = lin >> 3, c8 = (lin & 7) * 8;
    union { u16 s[8]; uint4 u; } pk;
#pragma unroll
    for (int k = 0; k < 8; k++) {
      int p = c8 + k, blk = p >> 5, q = p & 31;
      int nl = blk * 32 + ((q >> 2) & 1) * 16 + (q >> 3) * 4 + (q & 3);
      pk.s[k] = tile[nl][dv];
    }
    *(uint4*)(vT + ((size_t)bh * DH_ + dv) * N_ + nc + c8) = pk.u;
  }
}

// ---------------- global max of k features per (b,h) — LDS-free ----------------
__global__ __launch_bounds__(256) void k_kmax2(
    const u16* __restrict__ kb, const u16* __restrict__ projb, unsigned* __restrict__ mbuf) {
  const int bh = blockIdx.y, b = bh / H_, h = bh - b * H_;
  const int n0 = blockIdx.x * 256;
  const int t = threadIdx.x, lane = t & 63, wv = t >> 6;
  const int lm = lane & 15, lq = lane >> 4;
  const u16* kbase = kb + (size_t)(b * N_ + n0 + wv * 64) * HID_ + h * DH_;
  short8 af0[4], af1[4];
#pragma unroll
  for (int mt = 0; mt < 4; mt++) {
    const u16* p = kbase + (size_t)(mt * 16 + lm) * HID_ + lq * 8;
    af0[mt] = *(const short8*)p;
    af1[mt] = *(const short8*)(p + 32);
  }
  float mx = -3e38f;
  for (int ct = 0; ct < 17; ct++) {
    const u16* pp = projb + (ct * 16 + lm) * DH_ + lq * 8;
    short8 bf0 = *(const short8*)pp;
    short8 bf1 = *(const short8*)(pp + 32);
    bool valid = (ct < 16) || (lm < 10);
#pragma unroll
    for (int mt = 0; mt < 4; mt++) {
      floatx4 a = __builtin_amdgcn_mfma_f32_16x16x32_bf16(af0[mt], bf0, (floatx4){0.f,0.f,0.f,0.f}, 0, 0, 0);
      a = __builtin_amdgcn_mfma_f32_16x16x32_bf16(af1[mt], bf1, a, 0, 0, 0);
      if (valid) {
#pragma unroll
        for (int r = 0; r < 4; r++) mx = fmaxf(mx, a[r]);
      }
    }
  }
#pragma unroll
  for (int o = 1; o < 64; o <<= 1) mx = fmaxf(mx, __shfl_xor(mx, o));
  if (lane == 0) atomicMax(&mbuf[bh], fmap(mx));
}

// ---------------- kp features -> kpT[bh][j][n] (perm n-order) + ksum — LDS-free ----------------
__global__ __launch_bounds__(256) void k_kp(
    const u16* __restrict__ kb, const u16* __restrict__ projb, const unsigned* __restrict__ mbuf,
    u16* __restrict__ kpT, float* __restrict__ ksum) {
  const int bh = blockIdx.y, b = bh / H_, h = bh - b * H_;
  const int n0 = blockIdx.x * 256;
  const int t = threadIdx.x, lane = t & 63, wv = t >> 6;
  const int lm = lane & 15, lq = lane >> 4;
  const float m = funmap(mbuf[bh]);
  const u16* kbase = kb + (size_t)(b * N_ + n0 + wv * 64) * HID_ + h * DH_;
  const size_t kpbase = (size_t)bh * NBP_ * N_;
  const int nw = n0 + wv * 64;
  float kacc[18];
#pragma unroll
  for (int ct = 0; ct < 18; ct++) kacc[ct] = 0.f;
  uint2 stash[18];

  for (int pair = 0; pair < 2; pair++) {
#pragma unroll
    for (int sub = 0; sub < 2; sub++) {
      const int mt = pair * 2 + sub;
      const u16* prow = kbase + (size_t)(mt * 16 + lm) * HID_ + lq * 8;
      short8 af0 = *(const short8*)prow;
      short8 af1 = *(const short8*)(prow + 32);
      float rs = 0.f;
#pragma unroll
      for (int i = 0; i < 8; i++) { float f = b2f(((const u16*)&af0)[i]); rs += f * f; }
#pragma unroll
      for (int i = 0; i < 8; i++) { float f = b2f(((const u16*)&af1)[i]); rs += f * f; }
      rs += __shfl_xor(rs, 16);
      rs += __shfl_xor(rs, 32);
      float dg[4];
#pragma unroll
      for (int r = 0; r < 4; r++) dg[r] = 0.0625f * __shfl(rs, lq * 4 + r);
#pragma unroll
      for (int ct = 0; ct < 18; ct++) {
        floatx4 a;
        if (ct < 17) {
          const u16* pp = projb + (ct * 16 + lm) * DH_ + lq * 8;
          short8 bf0 = *(const short8*)pp;
          short8 bf1 = *(const short8*)(pp + 32);
          a = __builtin_amdgcn_mfma_f32_16x16x32_bf16(af0, bf0, (floatx4){0.f,0.f,0.f,0.f}, 0, 0, 0);
          a = __builtin_amdgcn_mfma_f32_16x16x32_bf16(af1, bf1, a, 0, 0, 0);
        } else {
          a = (floatx4){0.f, 0.f, 0.f, 0.f};
        }
        bool valid = (ct < 16) || (ct == 16 && lm < 10);
        union { u16 s[4]; uint2 u; } pk;
        float kss = 0.f;
#pragma unroll
        for (int r = 0; r < 4; r++) {
          float val = valid ? RATIO_ * (__expf(a[r] - dg[r] - m) + EPS_) : 0.f;
          kss += val;
          pk.s[r] = f2b(val);
        }
        kacc[ct] += kss;
        if (sub == 0) {
          stash[ct] = pk.u;
        } else {
          uint4 w4 = make_uint4(stash[ct].x, stash[ct].y, pk.u.x, pk.u.y);
          *(uint4*)(kpT + kpbase + (size_t)(ct * 16 + lm) * N_ + nw + pair * 32 + lq * 8) = w4;
        }
      }
    }
  }
#pragma unroll
  for (int ct = 0; ct < 18; ct++) {
    float v = kacc[ct];
    v += __shfl_xor(v, 16);
    v += __shfl_xor(v, 32);
    if (lq == 0) atomicAdd(&ksum[bh * NBP_ + ct * 16 + lm], v);
  }
}

// ---------------- ctxT[bh][dv][j] = sum_n vT[dv][n]*kpT[j][n] — pure GEMM, k-split ----------------
__global__ __launch_bounds__(256) void k_ctx2(
    const u16* __restrict__ vT, const u16* __restrict__ kpT, float* __restrict__ ctxTf) {
  const int bh = blockIdx.y;
  const int kc = blockIdx.x * 256;
  const int t = threadIdx.x, lane = t & 63, wv = t >> 6;
  const int lm = lane & 15, lq = lane >> 4;
  const u16* Ab = vT + ((size_t)bh * DH_ + wv * 16 + lm) * N_ + kc + lq * 8;
  const u16* Bb = kpT + (size_t)bh * NBP_ * N_ + kc + lq * 8;
  floatx4 acc[18];
#pragma unroll
  for (int ct = 0; ct < 18; ct++) acc[ct] = (floatx4){0.f, 0.f, 0.f, 0.f};
  for (int ks = 0; ks < 8; ks++) {
    short8 av = *(const short8*)(Ab + ks * 32);
#pragma unroll
    for (int ct = 0; ct < 18; ct++) {
      short8 bv = *(const short8*)(Bb + (size_t)(ct * 16 + lm) * N_ + ks * 32);
      acc[ct] = __builtin_amdgcn_mfma_f32_16x16x32_bf16(av, bv, acc[ct], 0, 0, 0);
    }
  }
#pragma unroll
  for (int ct = 0; ct < 18; ct++) {
#pragma unroll
    for (int r = 0; r < 4; r++)
      atomicAdd(&ctxTf[((size_t)bh * DH_ + wv * 16 + lq * 4 + r) * NBP_ + ct * 16 + lm], acc[ct][r]);
  }
}

__global__ void k_cvt_ctx(const float* __restrict__ src, u16* __restrict__ dst) {
  int i = blockIdx.x * 256 + threadIdx.x;
  if (i < B_ * H_ * DH_ * NBP_) dst[i] = f2b(src[i]);
}

// ---------------- fused q-features + out GEMM ----------------
__global__ __launch_bounds__(256) void k_out2(
    const u16* __restrict__ qb, const u16* __restrict__ projb,
    const u16* __restrict__ ctxb, const float* __restrict__ ksum,
    float* __restrict__ outp) {
  __shared__ u16 qpl[4][16][296];   // per-wave private 16x288 (+8 pad)
  const int bh = blockIdx.y, b = bh / H_, h = bh - b * H_;
  const int n0 = blockIdx.x * 256;
  const int t = threadIdx.x, lane = t & 63, wv = t >> 6;
  const int lm = lane & 15, lq = lane >> 4;
  const u16* qbase = qb + (size_t)(b * N_ + n0 + wv * 64) * HID_ + h * DH_;
  const u16* cb = ctxb + (size_t)bh * DH_ * NBP_;
  const float* ksb = ksum + bh * NBP_;

  for (int mt = 0; mt < 4; mt++) {
    const u16* prow = qbase + (size_t)(mt * 16 + lm) * HID_ + lq * 8;
    short8 af0 = *(const short8*)prow;
    short8 af1 = *(const short8*)(prow + 32);
    float rs = 0.f;
#pragma unroll
    for (int i = 0; i < 8; i++) { float f = b2f(((const u16*)&af0)[i]); rs += f * f; }
#pragma unroll
    for (int i = 0; i < 8; i++) { float f = b2f(((const u16*)&af1)[i]); rs += f * f; }
    rs += __shfl_xor(rs, 16);
    rs += __shfl_xor(rs, 32);
    float dg[4];
#pragma unroll
    for (int r = 0; r < 4; r++) dg[r] = 0.0625f * __shfl(rs, lq * 4 + r);

    floatx4 dd[17];
    float rm[4] = {-3e38f, -3e38f, -3e38f, -3e38f};
#pragma unroll
    for (int ct = 0; ct < 17; ct++) {
      const u16* pp = projb + (ct * 16 + lm) * DH_ + lq * 8;
      short8 bf0 = *(const short8*)pp;
      short8 bf1 = *(const short8*)(pp + 32);
      floatx4 a = __builtin_amdgcn_mfma_f32_16x16x32_bf16(af0, bf0, (floatx4){0.f,0.f,0.f,0.f}, 0, 0, 0);
      a = __builtin_amdgcn_mfma_f32_16x16x32_bf16(af1, bf1, a, 0, 0, 0);
      dd[ct] = a;
      if ((ct < 16) || (lm < 10)) {
#pragma unroll
        for (int r = 0; r < 4; r++) rm[r] = fmaxf(rm[r], a[r]);
      }
    }
#pragma unroll
    for (int o = 1; o < 16; o <<= 1) {
#pragma unroll
      for (int r = 0; r < 4; r++) rm[r] = fmaxf(rm[r], __shfl_xor(rm[r], o));
    }
    float dpart[4] = {0.f, 0.f, 0.f, 0.f};
#pragma unroll
    for (int ct = 0; ct < 18; ct++) {
      floatx4 a = (ct < 17) ? dd[ct] : (floatx4){0.f, 0.f, 0.f, 0.f};
      bool valid = (ct < 16) || (ct == 16 && lm < 10);
      float ksv = ksb[ct * 16 + lm];
#pragma unroll
      for (int r = 0; r < 4; r++) {
        float qpv = valid ? RATIO_ * (__expf(a[r] - dg[r] - rm[r]) + EPS_) : 0.f;
        dpart[r] += qpv * ksv;
        qpl[wv][lq * 4 + r][ct * 16 + lm] = f2b(qpv);
      }
    }
#pragma unroll
    for (int o = 1; o < 16; o <<= 1) {
#pragma unroll
      for (int r = 0; r < 4; r++) dpart[r] += __shfl_xor(dpart[r], o);
    }
    float dinv[4];
#pragma unroll
    for (int r = 0; r < 4; r++) dinv[r] = 1.f / dpart[r];

    floatx4 ao[4];
#pragma unroll
    for (int dt = 0; dt < 4; dt++) ao[dt] = (floatx4){0.f, 0.f, 0.f, 0.f};
#pragma unroll
    for (int ks9 = 0; ks9 < 9; ks9++) {
      short8 aq = *(const short8*)&qpl[wv][lm][ks9 * 32 + lq * 8];
#pragma unroll
      for (int dt = 0; dt < 4; dt++) {
        short8 bc = *(const short8*)(cb + (size_t)(dt * 16 + lm) * NBP_ + ks9 * 32 + lq * 8);
        ao[dt] = __builtin_amdgcn_mfma_f32_16x16x32_bf16(aq, bc, ao[dt], 0, 0, 0);
      }
    }
#pragma unroll
    for (int dt = 0; dt < 4; dt++) {
#pragma unroll
      for (int r = 0; r < 4; r++) {
        int n = n0 + wv * 64 + mt * 16 + lq * 4 + r;
        outp[((size_t)(b * N_ + n)) * HID_ + h * DH_ + dt * 16 + lm] = ao[dt][r] * dinv[r];
      }
    }
  }
}

extern "C" void kernel_launch(void* const* d_in, const int* in_sizes, int n_in,
                              void* d_out, int out_size, void* d_ws, size_t ws_size,
                              hipStream_t stream) {
  (void)in_sizes; (void)n_in; (void)out_size; (void)ws_size;
  const float* hs   = (const float*)d_in[0];
  const float* Wq   = (const float*)d_in[1];
  const float* bq   = (const float*)d_in[2];
  const float* Wk   = (const float*)d_in[3];
  const float* bk   = (const float*)d_in[4];
  const float* Wv   = (const float*)d_in[5];
  const float* bv   = (const float*)d_in[6];
  const float* proj = (const float*)d_in[7];

  char* w = (char*)d_ws;
  u16* hsb   = (u16*)w;  w += (size_t)16384 * 768 * 2;     // aliased by vT later
  u16* wb3   = (u16*)w;  w += (size_t)3 * 768 * 768 * 2;
  u16* projb = (u16*)w;  w += (size_t)NBP_ * 64 * 2;
  u16* qb    = (u16*)w;  w += (size_t)16384 * 768 * 2;
  u16* kb    = (u16*)w;  w += (size_t)16384 * 768 * 2;
  u16* vb    = (u16*)w;  w += (size_t)16384 * 768 * 2;
  u16* kpT   = (u16*)w;  w += (size_t)48 * NBP_ * N_ * 2;  // 113 MB
  float* ksum  = (float*)w; w += (size_t)48 * NBP_ * 4;
  float* ctxTf = (float*)w; w += (size_t)48 * DH_ * NBP_ * 4;
  u16* ctxTb = (u16*)w;  w += (size_t)48 * DH_ * NBP_ * 2;
  unsigned* mbuf = (unsigned*)w;
  u16* vT = hsb;  // hs staging dead after k_qkv; k_vt runs after

  hipLaunchKernelGGL(k_convert4, dim3(12288), dim3(256), 0, stream, (const float4*)hs, (uint2*)hsb, 16384 * 768 / 4);
  hipLaunchKernelGGL(k_convert4, dim3(576), dim3(256), 0, stream, (const float4*)Wq, (uint2*)wb3, 768 * 768 / 4);
  hipLaunchKernelGGL(k_convert4, dim3(576), dim3(256), 0, stream, (const float4*)Wk, (uint2*)(wb3 + 768 * 768), 768 * 768 / 4);
  hipLaunchKernelGGL(k_convert4, dim3(576), dim3(256), 0, stream, (const float4*)Wv, (uint2*)(wb3 + 2 * 768 * 768), 768 * 768 / 4);
  hipLaunchKernelGGL(k_prep_proj, dim3(72), dim3(256), 0, stream, proj, projb);
  int nz = 48 * NBP_ + 48 * DH_ * NBP_;  // ksum + ctxTf contiguous
  hipLaunchKernelGGL(k_init, dim3((nz + 255) / 256), dim3(256), 0, stream, ksum, mbuf, nz);
  hipLaunchKernelGGL(k_qkv, dim3(128, 18), dim3(256), 0, stream, hsb, wb3, bq, bk, bv, qb, kb, vb);
  hipLaunchKernelGGL(k_vt, dim3(64, 48), dim3(256), 0, stream, vb, vT);
  hipLaunchKernelGGL(k_kmax2, dim3(16, 48), dim3(256), 0, stream, kb, projb, mbuf);
  hipLaunchKernelGGL(k_kp, dim3(16, 48), dim3(256), 0, stream, kb, projb, mbuf, kpT, ksum);
  hipLaunchKernelGGL(k_ctx2, dim3(16, 48), dim3(256), 0, stream, vT, kpT, ctxTf);
  hipLaunchKernelGGL(k_cvt_ctx, dim3((48 * DH_ * NBP_ + 255) / 256), dim3(256), 0, stream, ctxTf, ctxTb);
  hipLaunchKernelGGL(k_out2, dim3(16, 48), dim3(256), 0, stream, qb, projb, ctxTb, ksum, (float*)d_out);
}

// Round 3
// 422.912 us; speedup vs baseline: 1.0807x; 1.0807x over previous
//
#include <hip/hip_runtime.h>
#include <hip/hip_bf16.h>
#include <stdint.h>

#define B_   4
#define N_   4096
#define HID_ 768
#define H_   12
#define DH_  64
#define NB_  266
#define NBP_ 288          // NB padded to multiple of 32
#define EPS_ 1e-4f
#define RATIO_ 0.06131393f  // 266^-0.5

typedef unsigned short u16;
typedef __attribute__((ext_vector_type(8))) short short8;
typedef __attribute__((ext_vector_type(4))) float floatx4;

__device__ __forceinline__ u16 f2b(float f) {
  __hip_bfloat16 h = __float2bfloat16(f);
  return *reinterpret_cast<u16*>(&h);
}
__device__ __forceinline__ float b2f(u16 u) {
  union { unsigned u; float f; } x; x.u = ((unsigned)u) << 16; return x.f;
}
__device__ __forceinline__ unsigned fmap(float x) {
  unsigned u = __float_as_uint(x);
  return (u & 0x80000000u) ? ~u : (u | 0x80000000u);
}
__device__ __forceinline__ float funmap(unsigned u) {
  unsigned b = (u & 0x80000000u) ? (u & 0x7FFFFFFFu) : ~u;
  return __uint_as_float(b);
}
__device__ __forceinline__ void gl16(const u16* g, u16* l) {
  __builtin_amdgcn_global_load_lds(
      (const __attribute__((address_space(1))) void*)g,
      (__attribute__((address_space(3))) void*)l, 16, 0, 0);
}

// ---------------- converts / init ----------------
__global__ void k_convert4(const float4* __restrict__ src, uint2* __restrict__ dst, int n4) {
  int i = blockIdx.x * 256 + threadIdx.x;
  if (i >= n4) return;
  float4 v = src[i];
  union { u16 s[4]; uint2 u; } pk;
  pk.s[0] = f2b(v.x); pk.s[1] = f2b(v.y); pk.s[2] = f2b(v.z); pk.s[3] = f2b(v.w);
  dst[i] = pk.u;
}

__global__ void k_prep_proj(const float* __restrict__ proj, u16* __restrict__ dst) {
  int i = blockIdx.x * 256 + threadIdx.x;          // NBP_*DH_ = 18432
  if (i >= NBP_ * DH_) return;
  int j = i / DH_, d = i - j * DH_;
  float v = (j < NB_) ? proj[j * DH_ + d] * 0.35355339059327373f : 0.f;  // fold dn
  dst[i] = f2b(v);
}

__global__ void k_init(float* __restrict__ zf, unsigned* __restrict__ mbuf, int nf) {
  int i = blockIdx.x * 256 + threadIdx.x;
  if (i < nf) zf[i] = 0.f;
  if (i < B_ * H_) mbuf[i] = 0u;
}

// ---------------- QKV GEMM (m97 structure); v written TRANSPOSED to vT[bh][dv][n] ----------------
__global__ __launch_bounds__(256) void k_qkv(
    const u16* __restrict__ hsb, const u16* __restrict__ wb,
    const float* __restrict__ bq, const float* __restrict__ bk, const float* __restrict__ bv,
    u16* __restrict__ qb, u16* __restrict__ kb, u16* __restrict__ vT) {
  __shared__ u16 At[128 * 32];
  __shared__ u16 Bt[128 * 32];
  const int m0 = blockIdx.x * 128;
  const int bn = blockIdx.y;
  const int sel = bn / 6;                  // 0:q 1:k 2:v
  const int or0 = (bn % 6) * 128;
  const u16* W = wb + (size_t)sel * HID_ * HID_;
  const int t = threadIdx.x, lane = t & 63, wv = t >> 6;
  const int wr = (wv >> 1) * 64, wc = (wv & 1) * 64;
  const int lm = lane & 15, lq = lane >> 4;
  const int srow = wv * 32 + (lane >> 2);
  const int scol = (lane & 3) * 8;
  const u16* gA0 = hsb + (size_t)(m0 + srow) * HID_ + scol;
  const u16* gA1 = gA0 + 16 * HID_;
  const u16* gB0 = W + (size_t)(or0 + srow) * HID_ + scol;
  const u16* gB1 = gB0 + 16 * HID_;
  u16* lA = At + wv * 1024;
  u16* lB = Bt + wv * 1024;
  floatx4 acc[4][4];
#pragma unroll
  for (int i = 0; i < 4; i++)
#pragma unroll
    for (int j = 0; j < 4; j++) acc[i][j] = (floatx4){0.f, 0.f, 0.f, 0.f};

  for (int k0 = 0; k0 < HID_; k0 += 32) {
    __syncthreads();
    gl16(gA0 + k0, lA);
    gl16(gA1 + k0, lA + 512);
    gl16(gB0 + k0, lB);
    gl16(gB1 + k0, lB + 512);
    __syncthreads();
    short8 af[4], bfr[4];
#pragma unroll
    for (int mt = 0; mt < 4; mt++) af[mt] = *(const short8*)&At[(wr + mt * 16 + lm) * 32 + lq * 8];
#pragma unroll
    for (int nt = 0; nt < 4; nt++) bfr[nt] = *(const short8*)&Bt[(wc + nt * 16 + lm) * 32 + lq * 8];
#pragma unroll
    for (int mt = 0; mt < 4; mt++)
#pragma unroll
      for (int nt = 0; nt < 4; nt++)
        acc[mt][nt] = __builtin_amdgcn_mfma_f32_16x16x32_bf16(af[mt], bfr[nt], acc[mt][nt], 0, 0, 0);
  }
  if (sel < 2) {
    const float* bias = (sel == 0) ? bq : bk;
    u16* dst = (sel == 0) ? qb : kb;
#pragma unroll
    for (int mt = 0; mt < 4; mt++) {
#pragma unroll
      for (int nt = 0; nt < 4; nt++) {
        int lc = or0 + wc + nt * 16 + lm;
        float bb = bias[lc];
#pragma unroll
        for (int r = 0; r < 4; r++) {
          int row = m0 + wr + mt * 16 + lq * 4 + r;
          dst[(size_t)row * HID_ + lc] = f2b(acc[mt][nt][r] + bb);
        }
      }
    }
  } else {
    // v: store transposed -> vT[(b*12+h)*64+dv][n], 4 consecutive n per lane (8B store)
#pragma unroll
    for (int mt = 0; mt < 4; mt++) {
#pragma unroll
      for (int nt = 0; nt < 4; nt++) {
        int lc = or0 + wc + nt * 16 + lm;
        int hh = lc >> 6, dv = lc & 63;
        float bb = bv[lc];
        int rowbase = m0 + wr + mt * 16 + lq * 4;
        int b = rowbase >> 12, n = rowbase & 4095;
        union { u16 s[4]; uint2 u; } pk;
#pragma unroll
        for (int r = 0; r < 4; r++) pk.s[r] = f2b(acc[mt][nt][r] + bb);
        *(uint2*)(vT + ((size_t)(b * H_ + hh) * DH_ + dv) * N_ + n) = pk.u;
      }
    }
  }
}

// ---------------- global max of k features per (b,h) — LDS-free ----------------
__global__ __launch_bounds__(256) void k_kmax2(
    const u16* __restrict__ kb, const u16* __restrict__ projb, unsigned* __restrict__ mbuf) {
  const int bh = blockIdx.y, b = bh / H_, h = bh - b * H_;
  const int n0 = blockIdx.x * 256;
  const int t = threadIdx.x, lane = t & 63, wv = t >> 6;
  const int lm = lane & 15, lq = lane >> 4;
  const u16* kbase = kb + (size_t)(b * N_ + n0 + wv * 64) * HID_ + h * DH_;
  short8 af0[4], af1[4];
#pragma unroll
  for (int mt = 0; mt < 4; mt++) {
    const u16* p = kbase + (size_t)(mt * 16 + lm) * HID_ + lq * 8;
    af0[mt] = *(const short8*)p;
    af1[mt] = *(const short8*)(p + 32);
  }
  float mx = -3e38f;
  for (int ct = 0; ct < 17; ct++) {
    const u16* pp = projb + (ct * 16 + lm) * DH_ + lq * 8;
    short8 bf0 = *(const short8*)pp;
    short8 bf1 = *(const short8*)(pp + 32);
    bool valid = (ct < 16) || (lm < 10);
#pragma unroll
    for (int mt = 0; mt < 4; mt++) {
      floatx4 a = __builtin_amdgcn_mfma_f32_16x16x32_bf16(af0[mt], bf0, (floatx4){0.f,0.f,0.f,0.f}, 0, 0, 0);
      a = __builtin_amdgcn_mfma_f32_16x16x32_bf16(af1[mt], bf1, a, 0, 0, 0);
      if (valid) {
#pragma unroll
        for (int r = 0; r < 4; r++) mx = fmaxf(mx, a[r]);
      }
    }
  }
#pragma unroll
  for (int o = 1; o < 64; o <<= 1) mx = fmaxf(mx, __shfl_xor(mx, o));
  if (lane == 0) atomicMax(&mbuf[bh], fmap(mx));
}

// ---------------- fused k features + ctx GEMM ----------------
// block: (n-split 16, bh 48); 256 thr. Per 64-n iter: phase A computes kp tile
// [288 j][64 n] into LDS (wave = one n-16 tile); phase B: ctxT[dv][j] MFMA with
// A = vT from global, B = kp from LDS (wave = one dv-16 tile).
__global__ __launch_bounds__(256) void k_ctx3(
    const u16* __restrict__ kb, const u16* __restrict__ vT, const u16* __restrict__ projb,
    const unsigned* __restrict__ mbuf, float* __restrict__ ctxTf, float* __restrict__ ksum) {
  __shared__ u16 kpl[NBP_ * 72];    // [j][72], 16B-aligned rows, conflict-free b128 phases
  const int bh = blockIdx.y, b = bh / H_, h = bh - b * H_;
  const int n0 = blockIdx.x * 256;
  const int t = threadIdx.x, lane = t & 63, wv = t >> 6;
  const int lm = lane & 15, lq = lane >> 4;
  const float m = funmap(mbuf[bh]);
  const u16* vTb = vT + ((size_t)bh * DH_ + wv * 16 + lm) * N_;
  floatx4 acc[18];
#pragma unroll
  for (int jt = 0; jt < 18; jt++) acc[jt] = (floatx4){0.f, 0.f, 0.f, 0.f};
  float kacc[17];
#pragma unroll
  for (int ct = 0; ct < 17; ct++) kacc[ct] = 0.f;

  for (int it = 0; it < 4; it++) {
    const int n64 = n0 + it * 64;
    __syncthreads();   // protect kpl from previous iter's phase-B readers
    // ---- phase A: features for n-16 tile (wave wv) ----
    {
      const int row = n64 + wv * 16 + lm;
      const u16* kr = kb + ((size_t)(b * N_) + row) * HID_ + h * DH_ + lq * 8;
      short8 af0 = *(const short8*)kr;
      short8 af1 = *(const short8*)(kr + 32);
      float rs = 0.f;
#pragma unroll
      for (int i = 0; i < 8; i++) { float f = b2f(((const u16*)&af0)[i]); rs += f * f; }
#pragma unroll
      for (int i = 0; i < 8; i++) { float f = b2f(((const u16*)&af1)[i]); rs += f * f; }
      rs += __shfl_xor(rs, 16);
      rs += __shfl_xor(rs, 32);
      float dg[4];
#pragma unroll
      for (int r = 0; r < 4; r++) dg[r] = 0.0625f * __shfl(rs, lq * 4 + r);
#pragma unroll
      for (int ct = 0; ct < 17; ct++) {
        const u16* pp = projb + (ct * 16 + lm) * DH_ + lq * 8;
        short8 bf0 = *(const short8*)pp;
        short8 bf1 = *(const short8*)(pp + 32);
        floatx4 a = __builtin_amdgcn_mfma_f32_16x16x32_bf16(af0, bf0, (floatx4){0.f,0.f,0.f,0.f}, 0, 0, 0);
        a = __builtin_amdgcn_mfma_f32_16x16x32_bf16(af1, bf1, a, 0, 0, 0);
        bool valid = (ct < 16) || (lm < 10);
        union { u16 s[4]; uint2 u; } pk;
        float kss = 0.f;
#pragma unroll
        for (int r = 0; r < 4; r++) {
          float val = valid ? RATIO_ * (__expf(a[r] - dg[r] - m) + EPS_) : 0.f;
          kss += val;
          pk.s[r] = f2b(val);
        }
        kacc[ct] += kss;
        *(uint2*)&kpl[(ct * 16 + lm) * 72 + wv * 16 + lq * 4] = pk.u;
      }
      *(uint2*)&kpl[(272 + lm) * 72 + wv * 16 + lq * 4] = make_uint2(0u, 0u);  // j pad rows
    }
    __syncthreads();
    // ---- phase B: ctx MFMA, wave = dv-16 tile (wv) ----
#pragma unroll
    for (int ns = 0; ns < 2; ns++) {
      short8 av = *(const short8*)(vTb + n64 + ns * 32 + lq * 8);
#pragma unroll
      for (int jt = 0; jt < 18; jt++) {
        short8 bf = *(const short8*)&kpl[(jt * 16 + lm) * 72 + ns * 32 + lq * 8];
        acc[jt] = __builtin_amdgcn_mfma_f32_16x16x32_bf16(av, bf, acc[jt], 0, 0, 0);
      }
    }
  }
  // ---- finish: ksum + ctx atomics ----
#pragma unroll
  for (int ct = 0; ct < 17; ct++) {
    float v = kacc[ct];
    v += __shfl_xor(v, 16);
    v += __shfl_xor(v, 32);
    if (lq == 0) atomicAdd(&ksum[bh * NBP_ + ct * 16 + lm], v);
  }
#pragma unroll
  for (int jt = 0; jt < 18; jt++) {
#pragma unroll
    for (int r = 0; r < 4; r++)
      atomicAdd(&ctxTf[((size_t)bh * DH_ + wv * 16 + lq * 4 + r) * NBP_ + jt * 16 + lm], acc[jt][r]);
  }
}

__global__ void k_cvt_ctx(const float* __restrict__ src, u16* __restrict__ dst) {
  int i = blockIdx.x * 256 + threadIdx.x;
  if (i < B_ * H_ * DH_ * NBP_) dst[i] = f2b(src[i]);
}

// ---------------- fused q-features + out GEMM ----------------
__global__ __launch_bounds__(256) void k_out2(
    const u16* __restrict__ qb, const u16* __restrict__ projb,
    const u16* __restrict__ ctxb, const float* __restrict__ ksum,
    float* __restrict__ outp) {
  __shared__ u16 qpl[4][16][296];   // per-wave private 16x288 (+8 pad)
  const int bh = blockIdx.y, b = bh / H_, h = bh - b * H_;
  const int n0 = blockIdx.x * 256;
  const int t = threadIdx.x, lane = t & 63, wv = t >> 6;
  const int lm = lane & 15, lq = lane >> 4;
  const u16* qbase = qb + (size_t)(b * N_ + n0 + wv * 64) * HID_ + h * DH_;
  const u16* cb = ctxb + (size_t)bh * DH_ * NBP_;
  const float* ksb = ksum + bh * NBP_;

  for (int mt = 0; mt < 4; mt++) {
    const u16* prow = qbase + (size_t)(mt * 16 + lm) * HID_ + lq * 8;
    short8 af0 = *(const short8*)prow;
    short8 af1 = *(const short8*)(prow + 32);
    float rs = 0.f;
#pragma unroll
    for (int i = 0; i < 8; i++) { float f = b2f(((const u16*)&af0)[i]); rs += f * f; }
#pragma unroll
    for (int i = 0; i < 8; i++) { float f = b2f(((const u16*)&af1)[i]); rs += f * f; }
    rs += __shfl_xor(rs, 16);
    rs += __shfl_xor(rs, 32);
    float dg[4];
#pragma unroll
    for (int r = 0; r < 4; r++) dg[r] = 0.0625f * __shfl(rs, lq * 4 + r);

    floatx4 dd[17];
    float rm[4] = {-3e38f, -3e38f, -3e38f, -3e38f};
#pragma unroll
    for (int ct = 0; ct < 17; ct++) {
      const u16* pp = projb + (ct * 16 + lm) * DH_ + lq * 8;
      short8 bf0 = *(const short8*)pp;
      short8 bf1 = *(const short8*)(pp + 32);
      floatx4 a = __builtin_amdgcn_mfma_f32_16x16x32_bf16(af0, bf0, (floatx4){0.f,0.f,0.f,0.f}, 0, 0, 0);
      a = __builtin_amdgcn_mfma_f32_16x16x32_bf16(af1, bf1, a, 0, 0, 0);
      dd[ct] = a;
      if ((ct < 16) || (lm < 10)) {
#pragma unroll
        for (int r = 0; r < 4; r++) rm[r] = fmaxf(rm[r], a[r]);
      }
    }
#pragma unroll
    for (int o = 1; o < 16; o <<= 1) {
#pragma unroll
      for (int r = 0; r < 4; r++) rm[r] = fmaxf(rm[r], __shfl_xor(rm[r], o));
    }
    float dpart[4] = {0.f, 0.f, 0.f, 0.f};
#pragma unroll
    for (int ct = 0; ct < 18; ct++) {
      floatx4 a = (ct < 17) ? dd[ct] : (floatx4){0.f, 0.f, 0.f, 0.f};
      bool valid = (ct < 16) || (ct == 16 && lm < 10);
      float ksv = ksb[ct * 16 + lm];
#pragma unroll
      for (int r = 0; r < 4; r++) {
        float qpv = valid ? RATIO_ * (__expf(a[r] - dg[r] - rm[r]) + EPS_) : 0.f;
        dpart[r] += qpv * ksv;
        qpl[wv][lq * 4 + r][ct * 16 + lm] = f2b(qpv);
      }
    }
#pragma unroll
    for (int o = 1; o < 16; o <<= 1) {
#pragma unroll
      for (int r = 0; r < 4; r++) dpart[r] += __shfl_xor(dpart[r], o);
    }
    float dinv[4];
#pragma unroll
    for (int r = 0; r < 4; r++) dinv[r] = 1.f / dpart[r];

    floatx4 ao[4];
#pragma unroll
    for (int dt = 0; dt < 4; dt++) ao[dt] = (floatx4){0.f, 0.f, 0.f, 0.f};
#pragma unroll
    for (int ks9 = 0; ks9 < 9; ks9++) {
      short8 aq = *(const short8*)&qpl[wv][lm][ks9 * 32 + lq * 8];
#pragma unroll
      for (int dt = 0; dt < 4; dt++) {
        short8 bc = *(const short8*)(cb + (size_t)(dt * 16 + lm) * NBP_ + ks9 * 32 + lq * 8);
        ao[dt] = __builtin_amdgcn_mfma_f32_16x16x32_bf16(aq, bc, ao[dt], 0, 0, 0);
      }
    }
#pragma unroll
    for (int dt = 0; dt < 4; dt++) {
#pragma unroll
      for (int r = 0; r < 4; r++) {
        int n = n0 + wv * 64 + mt * 16 + lq * 4 + r;
        outp[((size_t)(b * N_ + n)) * HID_ + h * DH_ + dt * 16 + lm] = ao[dt][r] * dinv[r];
      }
    }
  }
}

extern "C" void kernel_launch(void* const* d_in, const int* in_sizes, int n_in,
                              void* d_out, int out_size, void* d_ws, size_t ws_size,
                              hipStream_t stream) {
  (void)in_sizes; (void)n_in; (void)out_size; (void)ws_size;
  const float* hs   = (const float*)d_in[0];
  const float* Wq   = (const float*)d_in[1];
  const float* bq   = (const float*)d_in[2];
  const float* Wk   = (const float*)d_in[3];
  const float* bk   = (const float*)d_in[4];
  const float* Wv   = (const float*)d_in[5];
  const float* bv   = (const float*)d_in[6];
  const float* proj = (const float*)d_in[7];

  char* w = (char*)d_ws;
  u16* hsb   = (u16*)w;  w += (size_t)16384 * 768 * 2;
  u16* wb3   = (u16*)w;  w += (size_t)3 * 768 * 768 * 2;
  u16* projb = (u16*)w;  w += (size_t)NBP_ * 64 * 2;
  u16* qb    = (u16*)w;  w += (size_t)16384 * 768 * 2;
  u16* kb    = (u16*)w;  w += (size_t)16384 * 768 * 2;
  u16* vT    = (u16*)w;  w += (size_t)48 * DH_ * N_ * 2;   // 25 MB, [bh][dv][n]
  float* ksum  = (float*)w; w += (size_t)48 * NBP_ * 4;
  float* ctxTf = (float*)w; w += (size_t)48 * DH_ * NBP_ * 4;
  u16* ctxTb = (u16*)w;  w += (size_t)48 * DH_ * NBP_ * 2;
  unsigned* mbuf = (unsigned*)w;

  hipLaunchKernelGGL(k_convert4, dim3(12288), dim3(256), 0, stream, (const float4*)hs, (uint2*)hsb, 16384 * 768 / 4);
  hipLaunchKernelGGL(k_convert4, dim3(576), dim3(256), 0, stream, (const float4*)Wq, (uint2*)wb3, 768 * 768 / 4);
  hipLaunchKernelGGL(k_convert4, dim3(576), dim3(256), 0, stream, (const float4*)Wk, (uint2*)(wb3 + 768 * 768), 768 * 768 / 4);
  hipLaunchKernelGGL(k_convert4, dim3(576), dim3(256), 0, stream, (const float4*)Wv, (uint2*)(wb3 + 2 * 768 * 768), 768 * 768 / 4);
  hipLaunchKernelGGL(k_prep_proj, dim3(72), dim3(256), 0, stream, proj, projb);
  int nz = 48 * NBP_ + 48 * DH_ * NBP_;  // ksum + ctxTf contiguous
  hipLaunchKernelGGL(k_init, dim3((nz + 255) / 256), dim3(256), 0, stream, ksum, mbuf, nz);
  hipLaunchKernelGGL(k_qkv, dim3(128, 18), dim3(256), 0, stream, hsb, wb3, bq, bk, bv, qb, kb, vT);
  hipLaunchKernelGGL(k_kmax2, dim3(16, 48), dim3(256), 0, stream, kb, projb, mbuf);
  hipLaunchKernelGGL(k_ctx3, dim3(16, 48), dim3(256), 0, stream, kb, vT, projb, mbuf, ctxTf, ksum);
  hipLaunchKernelGGL(k_cvt_ctx, dim3((48 * DH_ * NBP_ + 255) / 256), dim3(256), 0, stream, ctxTf, ctxTb);
  hipLaunchKernelGGL(k_out2, dim3(16, 48), dim3(256), 0, stream, qb, projb, ctxTb, ksum, (float*)d_out);
}

// Round 4
// 404.827 us; speedup vs baseline: 1.1290x; 1.0447x over previous
//
#include <hip/hip_runtime.h>
#include <hip/hip_bf16.h>
#include <stdint.h>

#define B_   4
#define N_   4096
#define HID_ 768
#define H_   12
#define DH_  64
#define NB_  266
#define NBP_ 288          // NB padded to multiple of 32
#define EPS_ 1e-4f
#define RATIO_ 0.06131393f  // 266^-0.5

typedef unsigned short u16;
typedef __attribute__((ext_vector_type(8))) short short8;
typedef __attribute__((ext_vector_type(4))) float floatx4;

__device__ __forceinline__ u16 f2b(float f) {
  __hip_bfloat16 h = __float2bfloat16(f);
  return *reinterpret_cast<u16*>(&h);
}
__device__ __forceinline__ float b2f(u16 u) {
  union { unsigned u; float f; } x; x.u = ((unsigned)u) << 16; return x.f;
}
__device__ __forceinline__ unsigned fmap(float x) {
  unsigned u = __float_as_uint(x);
  return (u & 0x80000000u) ? ~u : (u | 0x80000000u);
}
__device__ __forceinline__ float funmap(unsigned u) {
  unsigned b = (u & 0x80000000u) ? (u & 0x7FFFFFFFu) : ~u;
  return __uint_as_float(b);
}
__device__ __forceinline__ void gl16(const u16* g, u16* l) {
  __builtin_amdgcn_global_load_lds(
      (const __attribute__((address_space(1))) void*)g,
      (__attribute__((address_space(3))) void*)l, 16, 0, 0);
}

// ---------------- fused prep: converts + proj prep + zero init (1 launch) ----------------
// block ranges: [0,12288) hs | [12288,14016) W | [14016,14088) proj | [14088,14966) zeros | 14966 mbuf
__global__ __launch_bounds__(256) void k_prep(
    const float4* __restrict__ hs, const float4* __restrict__ Wq,
    const float4* __restrict__ Wk, const float4* __restrict__ Wv,
    const float* __restrict__ proj,
    uint2* __restrict__ hsb, uint2* __restrict__ wb3, u16* __restrict__ projb,
    float4* __restrict__ zf, unsigned* __restrict__ mbuf) {
  int blk = blockIdx.x;
  const int t = threadIdx.x;
  if (blk < 12288) {
    int i = blk * 256 + t;
    float4 v = hs[i];
    union { u16 s[4]; uint2 u; } pk;
    pk.s[0] = f2b(v.x); pk.s[1] = f2b(v.y); pk.s[2] = f2b(v.z); pk.s[3] = f2b(v.w);
    hsb[i] = pk.u;
    return;
  }
  blk -= 12288;
  if (blk < 1728) {
    int i = blk * 256 + t;               // 0..442367, uniform sel per block
    int sel = i / 147456, j = i - sel * 147456;
    const float4* s = (sel == 0) ? Wq : (sel == 1) ? Wk : Wv;
    float4 v = s[j];
    union { u16 s4[4]; uint2 u; } pk;
    pk.s4[0] = f2b(v.x); pk.s4[1] = f2b(v.y); pk.s4[2] = f2b(v.z); pk.s4[3] = f2b(v.w);
    wb3[i] = pk.u;
    return;
  }
  blk -= 1728;
  if (blk < 72) {
    int i = blk * 256 + t;               // NBP_*DH_ = 18432 exact
    int j = i / DH_, d = i - j * DH_;
    float v = (j < NB_) ? proj[j * DH_ + d] * 0.35355339059327373f : 0.f;  // fold dn
    projb[i] = f2b(v);
    return;
  }
  blk -= 72;
  if (blk < 878) {
    int i = blk * 256 + t;
    if (i < 224640) zf[i] = (float4){0.f, 0.f, 0.f, 0.f};   // ksum + ctxTf
    return;
  }
  if (t < B_ * H_) mbuf[t] = 0u;
}

// ---------------- QKV GEMM: BK=64 as two BK=32 panels; v written transposed ----------------
__global__ __launch_bounds__(256) void k_qkv(
    const u16* __restrict__ hsb, const u16* __restrict__ wb,
    const float* __restrict__ bq, const float* __restrict__ bk, const float* __restrict__ bv,
    u16* __restrict__ qb, u16* __restrict__ kb, u16* __restrict__ vT) {
  __shared__ u16 At[2 * 128 * 32];   // [panel][row][32]
  __shared__ u16 Bt[2 * 128 * 32];
  const int m0 = blockIdx.x * 128;
  const int bn = blockIdx.y;
  const int sel = bn / 6;                  // 0:q 1:k 2:v
  const int or0 = (bn % 6) * 128;
  const u16* W = wb + (size_t)sel * HID_ * HID_;
  const int t = threadIdx.x, lane = t & 63, wv = t >> 6;
  const int wr = (wv >> 1) * 64, wc = (wv & 1) * 64;
  const int lm = lane & 15, lq = lane >> 4;
  // staging: per panel p, half i: row = wv*32 + i*16 + (lane>>2), col = p*32 + (lane&3)*8
  const int srow = wv * 32 + (lane >> 2);
  const int scol = (lane & 3) * 8;
  const u16* gA = hsb + (size_t)(m0 + srow) * HID_ + scol;
  const u16* gB = W + (size_t)(or0 + srow) * HID_ + scol;
  u16* lA = At + wv * 1024;
  u16* lB = Bt + wv * 1024;
  floatx4 acc[4][4];
#pragma unroll
  for (int i = 0; i < 4; i++)
#pragma unroll
    for (int j = 0; j < 4; j++) acc[i][j] = (floatx4){0.f, 0.f, 0.f, 0.f};

  for (int k0 = 0; k0 < HID_; k0 += 64) {
    __syncthreads();
#pragma unroll
    for (int p = 0; p < 2; p++) {
#pragma unroll
      for (int i = 0; i < 2; i++) {
        gl16(gA + k0 + p * 32 + i * 16 * HID_, lA + p * 4096 + i * 512);
        gl16(gB + k0 + p * 32 + i * 16 * HID_, lB + p * 4096 + i * 512);
      }
    }
    __syncthreads();
#pragma unroll
    for (int p = 0; p < 2; p++) {
      short8 af[4], bfr[4];
#pragma unroll
      for (int mt = 0; mt < 4; mt++) af[mt] = *(const short8*)&At[p * 4096 + (wr + mt * 16 + lm) * 32 + lq * 8];
#pragma unroll
      for (int nt = 0; nt < 4; nt++) bfr[nt] = *(const short8*)&Bt[p * 4096 + (wc + nt * 16 + lm) * 32 + lq * 8];
#pragma unroll
      for (int mt = 0; mt < 4; mt++)
#pragma unroll
        for (int nt = 0; nt < 4; nt++)
          acc[mt][nt] = __builtin_amdgcn_mfma_f32_16x16x32_bf16(af[mt], bfr[nt], acc[mt][nt], 0, 0, 0);
    }
  }
  if (sel < 2) {
    const float* bias = (sel == 0) ? bq : bk;
    u16* dst = (sel == 0) ? qb : kb;
#pragma unroll
    for (int mt = 0; mt < 4; mt++) {
#pragma unroll
      for (int nt = 0; nt < 4; nt++) {
        int lc = or0 + wc + nt * 16 + lm;
        float bb = bias[lc];
#pragma unroll
        for (int r = 0; r < 4; r++) {
          int row = m0 + wr + mt * 16 + lq * 4 + r;
          dst[(size_t)row * HID_ + lc] = f2b(acc[mt][nt][r] + bb);
        }
      }
    }
  } else {
#pragma unroll
    for (int mt = 0; mt < 4; mt++) {
#pragma unroll
      for (int nt = 0; nt < 4; nt++) {
        int lc = or0 + wc + nt * 16 + lm;
        int hh = lc >> 6, dv = lc & 63;
        float bb = bv[lc];
        int rowbase = m0 + wr + mt * 16 + lq * 4;
        int b = rowbase >> 12, n = rowbase & 4095;
        union { u16 s[4]; uint2 u; } pk;
#pragma unroll
        for (int r = 0; r < 4; r++) pk.s[r] = f2b(acc[mt][nt][r] + bb);
        *(uint2*)(vT + ((size_t)(b * H_ + hh) * DH_ + dv) * N_ + n) = pk.u;
      }
    }
  }
}

// ---------------- global max of k features per (b,h) — LDS-free ----------------
__global__ __launch_bounds__(256) void k_kmax2(
    const u16* __restrict__ kb, const u16* __restrict__ projb, unsigned* __restrict__ mbuf) {
  const int bh = blockIdx.y, b = bh / H_, h = bh - b * H_;
  const int n0 = blockIdx.x * 256;
  const int t = threadIdx.x, lane = t & 63, wv = t >> 6;
  const int lm = lane & 15, lq = lane >> 4;
  const u16* kbase = kb + (size_t)(b * N_ + n0 + wv * 64) * HID_ + h * DH_;
  short8 af0[4], af1[4];
#pragma unroll
  for (int mt = 0; mt < 4; mt++) {
    const u16* p = kbase + (size_t)(mt * 16 + lm) * HID_ + lq * 8;
    af0[mt] = *(const short8*)p;
    af1[mt] = *(const short8*)(p + 32);
  }
  float mx = -3e38f;
  for (int ct = 0; ct < 17; ct++) {
    const u16* pp = projb + (ct * 16 + lm) * DH_ + lq * 8;
    short8 bf0 = *(const short8*)pp;
    short8 bf1 = *(const short8*)(pp + 32);
    bool valid = (ct < 16) || (lm < 10);
#pragma unroll
    for (int mt = 0; mt < 4; mt++) {
      floatx4 a = __builtin_amdgcn_mfma_f32_16x16x32_bf16(af0[mt], bf0, (floatx4){0.f,0.f,0.f,0.f}, 0, 0, 0);
      a = __builtin_amdgcn_mfma_f32_16x16x32_bf16(af1[mt], bf1, a, 0, 0, 0);
      if (valid) {
#pragma unroll
        for (int r = 0; r < 4; r++) mx = fmaxf(mx, a[r]);
      }
    }
  }
#pragma unroll
  for (int o = 1; o < 64; o <<= 1) mx = fmaxf(mx, __shfl_xor(mx, o));
  if (lane == 0) atomicMax(&mbuf[bh], fmap(mx));
}

// ---------------- fused k features + ctx GEMM ----------------
__global__ __launch_bounds__(256) void k_ctx3(
    const u16* __restrict__ kb, const u16* __restrict__ vT, const u16* __restrict__ projb,
    const unsigned* __restrict__ mbuf, float* __restrict__ ctxTf, float* __restrict__ ksum) {
  __shared__ u16 kpl[NBP_ * 72];    // [j][72]
  const int bh = blockIdx.y, b = bh / H_, h = bh - b * H_;
  const int n0 = blockIdx.x * 256;
  const int t = threadIdx.x, lane = t & 63, wv = t >> 6;
  const int lm = lane & 15, lq = lane >> 4;
  const float m = funmap(mbuf[bh]);
  const u16* vTb = vT + ((size_t)bh * DH_ + wv * 16 + lm) * N_;
  floatx4 acc[18];
#pragma unroll
  for (int jt = 0; jt < 18; jt++) acc[jt] = (floatx4){0.f, 0.f, 0.f, 0.f};
  float kacc[17];
#pragma unroll
  for (int ct = 0; ct < 17; ct++) kacc[ct] = 0.f;

  for (int it = 0; it < 4; it++) {
    const int n64 = n0 + it * 64;
    __syncthreads();
    // ---- phase A: features for n-16 tile (wave wv) ----
    {
      const int row = n64 + wv * 16 + lm;
      const u16* kr = kb + ((size_t)(b * N_) + row) * HID_ + h * DH_ + lq * 8;
      short8 af0 = *(const short8*)kr;
      short8 af1 = *(const short8*)(kr + 32);
      float rs = 0.f;
#pragma unroll
      for (int i = 0; i < 8; i++) { float f = b2f(((const u16*)&af0)[i]); rs += f * f; }
#pragma unroll
      for (int i = 0; i < 8; i++) { float f = b2f(((const u16*)&af1)[i]); rs += f * f; }
      rs += __shfl_xor(rs, 16);
      rs += __shfl_xor(rs, 32);
      float dg[4];
#pragma unroll
      for (int r = 0; r < 4; r++) dg[r] = 0.0625f * __shfl(rs, lq * 4 + r);
#pragma unroll
      for (int ct = 0; ct < 17; ct++) {
        const u16* pp = projb + (ct * 16 + lm) * DH_ + lq * 8;
        short8 bf0 = *(const short8*)pp;
        short8 bf1 = *(const short8*)(pp + 32);
        floatx4 a = __builtin_amdgcn_mfma_f32_16x16x32_bf16(af0, bf0, (floatx4){0.f,0.f,0.f,0.f}, 0, 0, 0);
        a = __builtin_amdgcn_mfma_f32_16x16x32_bf16(af1, bf1, a, 0, 0, 0);
        bool valid = (ct < 16) || (lm < 10);
        union { u16 s[4]; uint2 u; } pk;
        float kss = 0.f;
#pragma unroll
        for (int r = 0; r < 4; r++) {
          float val = valid ? RATIO_ * (__expf(a[r] - dg[r] - m) + EPS_) : 0.f;
          kss += val;
          pk.s[r] = f2b(val);
        }
        kacc[ct] += kss;
        *(uint2*)&kpl[(ct * 16 + lm) * 72 + wv * 16 + lq * 4] = pk.u;
      }
      *(uint2*)&kpl[(272 + lm) * 72 + wv * 16 + lq * 4] = make_uint2(0u, 0u);
    }
    __syncthreads();
    // ---- phase B: ctx MFMA, wave = dv-16 tile ----
#pragma unroll
    for (int ns = 0; ns < 2; ns++) {
      short8 av = *(const short8*)(vTb + n64 + ns * 32 + lq * 8);
#pragma unroll
      for (int jt = 0; jt < 18; jt++) {
        short8 bf = *(const short8*)&kpl[(jt * 16 + lm) * 72 + ns * 32 + lq * 8];
        acc[jt] = __builtin_amdgcn_mfma_f32_16x16x32_bf16(av, bf, acc[jt], 0, 0, 0);
      }
    }
  }
#pragma unroll
  for (int ct = 0; ct < 17; ct++) {
    float v = kacc[ct];
    v += __shfl_xor(v, 16);
    v += __shfl_xor(v, 32);
    if (lq == 0) atomicAdd(&ksum[bh * NBP_ + ct * 16 + lm], v);
  }
#pragma unroll
  for (int jt = 0; jt < 18; jt++) {
#pragma unroll
    for (int r = 0; r < 4; r++)
      atomicAdd(&ctxTf[((size_t)bh * DH_ + wv * 16 + lq * 4 + r) * NBP_ + jt * 16 + lm], acc[jt][r]);
  }
}

__global__ void k_cvt_ctx(const float* __restrict__ src, u16* __restrict__ dst) {
  int i = blockIdx.x * 256 + threadIdx.x;
  if (i < B_ * H_ * DH_ * NBP_) dst[i] = f2b(src[i]);
}

// ---------------- fused q-features + out GEMM (two-pass, low VGPR) ----------------
__global__ __launch_bounds__(256) void k_out3(
    const u16* __restrict__ qb, const u16* __restrict__ projb,
    const u16* __restrict__ ctxb, const float* __restrict__ ksum,
    float* __restrict__ outp) {
  __shared__ u16 qpl[4][16][296];   // per-wave private 16x288 (+8 pad)
  const int bh = blockIdx.y, b = bh / H_, h = bh - b * H_;
  const int n0 = blockIdx.x * 256;
  const int t = threadIdx.x, lane = t & 63, wv = t >> 6;
  const int lm = lane & 15, lq = lane >> 4;
  const u16* qbase = qb + (size_t)(b * N_ + n0 + wv * 64) * HID_ + h * DH_;
  const u16* cb = ctxb + (size_t)bh * DH_ * NBP_;
  const float* ksb = ksum + bh * NBP_;
  float ksv[17];
#pragma unroll
  for (int ct = 0; ct < 17; ct++) ksv[ct] = ksb[ct * 16 + lm];

  for (int mt = 0; mt < 4; mt++) {
    const u16* prow = qbase + (size_t)(mt * 16 + lm) * HID_ + lq * 8;
    short8 af0 = *(const short8*)prow;
    short8 af1 = *(const short8*)(prow + 32);
    float rs = 0.f;
#pragma unroll
    for (int i = 0; i < 8; i++) { float f = b2f(((const u16*)&af0)[i]); rs += f * f; }
#pragma unroll
    for (int i = 0; i < 8; i++) { float f = b2f(((const u16*)&af1)[i]); rs += f * f; }
    rs += __shfl_xor(rs, 16);
    rs += __shfl_xor(rs, 32);
    float dg[4];
#pragma unroll
    for (int r = 0; r < 4; r++) dg[r] = 0.0625f * __shfl(rs, lq * 4 + r);

    // pass 1: row max only (no dd storage)
    float rm[4] = {-3e38f, -3e38f, -3e38f, -3e38f};
#pragma unroll
    for (int ct = 0; ct < 17; ct++) {
      const u16* pp = projb + (ct * 16 + lm) * DH_ + lq * 8;
      short8 bf0 = *(const short8*)pp;
      short8 bf1 = *(const short8*)(pp + 32);
      floatx4 a = __builtin_amdgcn_mfma_f32_16x16x32_bf16(af0, bf0, (floatx4){0.f,0.f,0.f,0.f}, 0, 0, 0);
      a = __builtin_amdgcn_mfma_f32_16x16x32_bf16(af1, bf1, a, 0, 0, 0);
      if ((ct < 16) || (lm < 10)) {
#pragma unroll
        for (int r = 0; r < 4; r++) rm[r] = fmaxf(rm[r], a[r]);
      }
    }
#pragma unroll
    for (int o = 1; o < 16; o <<= 1) {
#pragma unroll
      for (int r = 0; r < 4; r++) rm[r] = fmaxf(rm[r], __shfl_xor(rm[r], o));
    }
    // pass 2: recompute dd, exp, qp -> LDS, d partial
    float dpart[4] = {0.f, 0.f, 0.f, 0.f};
#pragma unroll
    for (int ct = 0; ct < 18; ct++) {
      floatx4 a;
      if (ct < 17) {
        const u16* pp = projb + (ct * 16 + lm) * DH_ + lq * 8;
        short8 bf0 = *(const short8*)pp;
        short8 bf1 = *(const short8*)(pp + 32);
        a = __builtin_amdgcn_mfma_f32_16x16x32_bf16(af0, bf0, (floatx4){0.f,0.f,0.f,0.f}, 0, 0, 0);
        a = __builtin_amdgcn_mfma_f32_16x16x32_bf16(af1, bf1, a, 0, 0, 0);
      } else {
        a = (floatx4){0.f, 0.f, 0.f, 0.f};
      }
      bool valid = (ct < 16) || (ct == 16 && lm < 10);
      float kv = (ct < 17) ? ksv[ct] : 0.f;
#pragma unroll
      for (int r = 0; r < 4; r++) {
        float qpv = valid ? RATIO_ * (__expf(a[r] - dg[r] - rm[r]) + EPS_) : 0.f;
        dpart[r] += qpv * kv;
        qpl[wv][lq * 4 + r][ct * 16 + lm] = f2b(qpv);
      }
    }
#pragma unroll
    for (int o = 1; o < 16; o <<= 1) {
#pragma unroll
      for (int r = 0; r < 4; r++) dpart[r] += __shfl_xor(dpart[r], o);
    }
    float dinv[4];
#pragma unroll
    for (int r = 0; r < 4; r++) dinv[r] = 1.f / dpart[r];

    floatx4 ao[4];
#pragma unroll
    for (int dt = 0; dt < 4; dt++) ao[dt] = (floatx4){0.f, 0.f, 0.f, 0.f};
#pragma unroll
    for (int ks9 = 0; ks9 < 9; ks9++) {
      short8 aq = *(const short8*)&qpl[wv][lm][ks9 * 32 + lq * 8];
#pragma unroll
      for (int dt = 0; dt < 4; dt++) {
        short8 bc = *(const short8*)(cb + (size_t)(dt * 16 + lm) * NBP_ + ks9 * 32 + lq * 8);
        ao[dt] = __builtin_amdgcn_mfma_f32_16x16x32_bf16(aq, bc, ao[dt], 0, 0, 0);
      }
    }
#pragma unroll
    for (int dt = 0; dt < 4; dt++) {
#pragma unroll
      for (int r = 0; r < 4; r++) {
        int n = n0 + wv * 64 + mt * 16 + lq * 4 + r;
        outp[((size_t)(b * N_ + n)) * HID_ + h * DH_ + dt * 16 + lm] = ao[dt][r] * dinv[r];
      }
    }
  }
}

extern "C" void kernel_launch(void* const* d_in, const int* in_sizes, int n_in,
                              void* d_out, int out_size, void* d_ws, size_t ws_size,
                              hipStream_t stream) {
  (void)in_sizes; (void)n_in; (void)out_size; (void)ws_size;
  const float* hs   = (const float*)d_in[0];
  const float* Wq   = (const float*)d_in[1];
  const float* bq   = (const float*)d_in[2];
  const float* Wk   = (const float*)d_in[3];
  const float* bk   = (const float*)d_in[4];
  const float* Wv   = (const float*)d_in[5];
  const float* bv   = (const float*)d_in[6];
  const float* proj = (const float*)d_in[7];

  char* w = (char*)d_ws;
  u16* hsb   = (u16*)w;  w += (size_t)16384 * 768 * 2;
  u16* wb3   = (u16*)w;  w += (size_t)3 * 768 * 768 * 2;
  u16* projb = (u16*)w;  w += (size_t)NBP_ * 64 * 2;
  u16* qb    = (u16*)w;  w += (size_t)16384 * 768 * 2;
  u16* kb    = (u16*)w;  w += (size_t)16384 * 768 * 2;
  u16* vT    = (u16*)w;  w += (size_t)48 * DH_ * N_ * 2;   // [bh][dv][n]
  float* ksum  = (float*)w; w += (size_t)48 * NBP_ * 4;
  float* ctxTf = (float*)w; w += (size_t)48 * DH_ * NBP_ * 4;
  u16* ctxTb = (u16*)w;  w += (size_t)48 * DH_ * NBP_ * 2;
  unsigned* mbuf = (unsigned*)w;

  hipLaunchKernelGGL(k_prep, dim3(14967), dim3(256), 0, stream,
                     (const float4*)hs, (const float4*)Wq, (const float4*)Wk, (const float4*)Wv,
                     proj, (uint2*)hsb, (uint2*)wb3, projb, (float4*)ksum, mbuf);
  hipLaunchKernelGGL(k_qkv, dim3(128, 18), dim3(256), 0, stream, hsb, wb3, bq, bk, bv, qb, kb, vT);
  hipLaunchKernelGGL(k_kmax2, dim3(16, 48), dim3(256), 0, stream, kb, projb, mbuf);
  hipLaunchKernelGGL(k_ctx3, dim3(16, 48), dim3(256), 0, stream, kb, vT, projb, mbuf, ctxTf, ksum);
  hipLaunchKernelGGL(k_cvt_ctx, dim3((48 * DH_ * NBP_ + 255) / 256), dim3(256), 0, stream, ctxTf, ctxTb);
  hipLaunchKernelGGL(k_out3, dim3(16, 48), dim3(256), 0, stream, qb, projb, ctxTb, ksum, (float*)d_out);
}